// Round 18
// baseline (162.326 us; speedup 1.0000x reference)
//
#include <hip/hip_runtime.h>

typedef float f32x4 __attribute__((ext_vector_type(4)));

// db4 reconstruction filters
#define G00 0.23037781330885523f
#define G01 0.7148465705525415f
#define G02 0.6308807679295904f
#define G03 -0.02798376941698385f
#define G04 -0.18703481171888114f
#define G05 0.030841381835986965f
#define G06 0.032883011666982945f
#define G07 -0.010597401784997278f

#define G10 -0.010597401784997278f
#define G11 -0.032883011666982945f
#define G12 0.030841381835986965f
#define G13 0.18703481171888114f
#define G14 -0.02798376941698385f
#define G15 -0.6308807679295904f
#define G16 0.7148465705525415f
#define G17 -0.23037781330885523f

// ===========================================================================
// Level-1 path (N=64): R7/R12 kernel, unchanged (verified best).
// ===========================================================================
template<int LOGN, bool NT>
__device__ __forceinline__ void phaseBC(f32x4* smem, float* __restrict__ out,
                                        int b, int d, int tile, int tid)
{
    constexpr int N = 1 << LOGN;
    constexpr int N4 = N / 4;
    constexpr int LOGN4 = LOGN - 2;
    constexpr int BELEMS = 2 * 32 * N4;
    constexpr int BITER  = BELEMS / 512;

    f32x4 ureg[BITER];
    #pragma unroll
    for (int it = 0; it < BITER; ++it) {
        int e = it * 512 + tid;
        int w4   = e & (N4 - 1);
        int rest = e >> LOGN4;
        int hl   = rest & 31;
        int qq   = rest >> 5;
        int ml = hl >> 1, pp = hl & 1;
        int ro = ml + pp + 3;
        float b0c = pp ? G00 : G01, b1c = pp ? G02 : G03;
        float b2c = pp ? G04 : G05, b3c = pp ? G06 : G07;
        float d0c = pp ? G10 : G11, d1c = pp ? G12 : G13;
        float d2c = pp ? G14 : G15, d3c = pp ? G16 : G17;
        int s0 = 2 * qq, s1 = s0 + 1;
        ureg[it] = b0c * smem[(s0 * 20 + ro    ) * N4 + w4]
                 + b1c * smem[(s0 * 20 + ro - 1) * N4 + w4]
                 + b2c * smem[(s0 * 20 + ro - 2) * N4 + w4]
                 + b3c * smem[(s0 * 20 + ro - 3) * N4 + w4]
                 + d0c * smem[(s1 * 20 + ro    ) * N4 + w4]
                 + d1c * smem[(s1 * 20 + ro - 1) * N4 + w4]
                 + d2c * smem[(s1 * 20 + ro - 2) * N4 + w4]
                 + d3c * smem[(s1 * 20 + ro - 3) * N4 + w4];
    }
    __syncthreads();
    #pragma unroll
    for (int it = 0; it < BITER; ++it) {
        smem[it * 512 + tid] = ureg[it];
    }
    __syncthreads();

    const float* ulf = (const float*)smem;
    float* orow_base = out + (((size_t)b * (2 * N) + d) * (2 * N) + (size_t)32 * tile) * (2 * N);
    for (int e = tid; e < 32 * (N / 2); e += 512) {
        int mw2 = e & (N / 2 - 1);
        int hl  = e >> (LOGN - 1);
        int mw  = mw2 * 2;
        const float* u0 = ulf + (size_t)hl * N;
        const float* u1 = ulf + (size_t)(32 + hl) * N;
        int mm2 = (mw - 2) & (N - 1), mm1 = (mw - 1) & (N - 1);
        int mp1 = (mw + 1) & (N - 1), mp2 = (mw + 2) & (N - 1), mp3 = (mw + 3) & (N - 1);
        float u0m2 = u0[mm2], u0m1 = u0[mm1], u00 = u0[mw];
        float u0p1 = u0[mp1], u0p2 = u0[mp2], u0p3 = u0[mp3];
        float u1m2 = u1[mm2], u1m1 = u1[mm1], u10 = u1[mw];
        float u1p1 = u1[mp1], u1p2 = u1[mp2], u1p3 = u1[mp3];
        f32x4 o;
        o.x = G01*u0p1 + G03*u00  + G05*u0m1 + G07*u0m2
            + G11*u1p1 + G13*u10  + G15*u1m1 + G17*u1m2;
        o.y = G00*u0p2 + G02*u0p1 + G04*u00  + G06*u0m1
            + G10*u1p2 + G12*u1p1 + G14*u10  + G16*u1m1;
        o.z = G01*u0p2 + G03*u0p1 + G05*u00  + G07*u0m1
            + G11*u1p2 + G13*u1p1 + G15*u10  + G17*u1m1;
        o.w = G00*u0p3 + G02*u0p2 + G04*u0p1 + G06*u00
            + G10*u1p3 + G12*u1p2 + G14*u1p1 + G16*u10;
        f32x4* dst = (f32x4*)(orow_base + (size_t)hl * (2 * N)) + mw2;
        if (NT) __builtin_nontemporal_store(o, dst);
        else    *dst = o;
    }
}

template<int LOGN, bool NT>
__global__ __launch_bounds__(512) void idwt3_fused2_k(
    const float* __restrict__ ll, const float* __restrict__ yh,
    float* __restrict__ out, int b0)
{
    constexpr int N = 1 << LOGN;
    constexpr int N4 = N / 4;
    constexpr int LOGN4 = LOGN - 2;
    constexpr int NN = N * N;
    constexpr size_t V = (size_t)N * N * N;
    constexpr int AELEMS = 4 * 20 * N4;
    constexpr int AITER  = (AELEMS + 511) / 512;

    __shared__ f32x4 smem[AELEMS];

    const int tid  = threadIdx.x;
    const int tile = blockIdx.x;
    const int mD   = blockIdx.y;
    const int b    = b0 + (int)blockIdx.z;

    const size_t q0 = (size_t)((mD - 2 + N) & (N - 1)) * NN;
    const size_t q1 = (size_t)((mD - 1 + N) & (N - 1)) * NN;
    const size_t q2 = (size_t)( mD                    ) * NN;
    const size_t q3 = (size_t)((mD + 1) & (N - 1)) * NN;
    const size_t q4 = (size_t)((mD + 2) & (N - 1)) * NN;

    const int h0in = 16 * tile - 2;
    const float* llb = ll + (size_t)b * V;
    const float* yb  = yh + (size_t)b * 7 * V;

    f32x4 treg[AITER];
    #pragma unroll
    for (int it = 0; it < AITER; ++it) {
        int e = it * 512 + tid;
        if (AELEMS % 512 != 0 && e >= AELEMS) continue;
        int w4 = e & (N4 - 1);
        int x  = e >> LOGN4;
        int pr = x / 20;
        int r  = x - 20 * pr;
        int hr = h0in + r;
        if (hr < 0) hr += N;
        if (hr >= N) hr -= N;
        const float* lo_base = (pr == 0) ? llb : (yb + (size_t)(2 * pr - 1) * V);
        const float* hi_base = yb + (size_t)(2 * pr) * V;
        int off = hr * N + w4 * 4;
        const float* lp = lo_base + off;
        const float* hp = hi_base + off;
        f32x4 Lm2 = *(const f32x4*)(lp + q0);
        f32x4 Lm1 = *(const f32x4*)(lp + q1);
        f32x4 L0c = *(const f32x4*)(lp + q2);
        f32x4 Lp1 = *(const f32x4*)(lp + q3);
        f32x4 Lp2 = *(const f32x4*)(lp + q4);
        f32x4 Hm2 = *(const f32x4*)(hp + q0);
        f32x4 Hm1 = *(const f32x4*)(hp + q1);
        f32x4 H0c = *(const f32x4*)(hp + q2);
        f32x4 Hp1 = *(const f32x4*)(hp + q3);
        f32x4 Hp2 = *(const f32x4*)(hp + q4);
        smem[e] = G01*Lp1 + G03*L0c + G05*Lm1 + G07*Lm2
                + G11*Hp1 + G13*H0c + G15*Hm1 + G17*Hm2;
        treg[it] = G00*Lp2 + G02*Lp1 + G04*L0c + G06*Lm1
                 + G10*Hp2 + G12*Hp1 + G14*H0c + G16*Hm1;
    }
    __syncthreads();

    phaseBC<LOGN, NT>(smem, out, b, 2 * mD, tile, tid);
    __syncthreads();

    #pragma unroll
    for (int it = 0; it < AITER; ++it) {
        int e = it * 512 + tid;
        if (AELEMS % 512 != 0 && e >= AELEMS) continue;
        smem[e] = treg[it];
    }
    __syncthreads();

    phaseBC<LOGN, NT>(smem, out, b, 2 * mD + 1, tile, tid);
}

// ===========================================================================
// Level-2 path (N=128): quad-plane kernel (R17) with __launch_bounds__(512,2)
// so the 15 stash f32x4s stay in registers instead of spilling/reloading.
// ===========================================================================
__device__ __forceinline__ void phaseBC_l2(f32x4* smem, float* __restrict__ out,
                                           int b, int d, int tile, int tid)
{
    // ---- Phase B: thread = (s, qq, w4); 4 h-outputs from 12 b128 reads.
    {
        const int w4 = tid & 31;
        const int qq = (tid >> 5) & 1;
        const int s  = tid >> 6;                     // [0,8)
        const f32x4* t0 = smem + ((2 * qq) * 20 + 2 * s) * 32 + w4;   // lo tile
        const f32x4* t1 = t0 + 20 * 32;                               // hi tile
        f32x4 r0 = t0[0],   r1 = t0[32],  r2 = t0[64];
        f32x4 r3 = t0[96],  r4 = t0[128], r5 = t0[160];
        f32x4 e0 = t1[0],   e1 = t1[32],  e2 = t1[64];
        f32x4 e3 = t1[96],  e4 = t1[128], e5 = t1[160];
        f32x4 u0r = G01*r3 + G03*r2 + G05*r1 + G07*r0
                  + G11*e3 + G13*e2 + G15*e1 + G17*e0;
        f32x4 u1r = G00*r4 + G02*r3 + G04*r2 + G06*r1
                  + G10*e4 + G12*e3 + G14*e2 + G16*e1;
        f32x4 u2r = G01*r4 + G03*r3 + G05*r2 + G07*r1
                  + G11*e4 + G13*e3 + G15*e2 + G17*e1;
        f32x4 u3r = G00*r5 + G02*r4 + G04*r3 + G06*r2
                  + G10*e5 + G12*e4 + G14*e3 + G16*e2;
        __syncthreads();                             // all tl reads complete
        f32x4* ub = smem + ((qq * 32 + 4 * s) * 33 + w4);
        ub[0]  = u0r;
        ub[33] = u1r;
        ub[66] = u2r;
        ub[99] = u3r;
    }
    __syncthreads();

    // ---- Phase C: b128 window reads (2 f32x4 per subband) + parity selects.
    float* orow_base = out + (((size_t)b * 256 + d) * 256 + (size_t)32 * tile) * 256;
    #pragma unroll
    for (int it = 0; it < 4; ++it) {
        int e  = it * 512 + tid;
        int ow = e & 63;                             // output f32x4 in row
        int hl = e >> 6;                             // [0,32)
        int odd = ow & 1;
        int i0 = ((2 * ow - 2) & 127) >> 2;          // first window f32x4
        int i1 = ((2 * ow + 3) & 127) >> 2;          // second window f32x4
        const f32x4* u0r = smem + (size_t)hl * 33;
        const f32x4* u1r = smem + (size_t)(32 + hl) * 33;
        f32x4 P  = u0r[i0], Q  = u0r[i1];
        f32x4 Pp = u1r[i0], Qp = u1r[i1];
        float w0 = odd ? P[0]  : P[2],  w1 = odd ? P[1]  : P[3];
        float w2 = odd ? P[2]  : Q[0],  w3 = odd ? P[3]  : Q[1];
        float w4 = odd ? Q[0]  : Q[2],  w5 = odd ? Q[1]  : Q[3];
        float x0 = odd ? Pp[0] : Pp[2], x1 = odd ? Pp[1] : Pp[3];
        float x2 = odd ? Pp[2] : Qp[0], x3 = odd ? Pp[3] : Qp[1];
        float x4 = odd ? Qp[0] : Qp[2], x5 = odd ? Qp[1] : Qp[3];
        f32x4 o;
        o[0] = G01*w3 + G03*w2 + G05*w1 + G07*w0
             + G11*x3 + G13*x2 + G15*x1 + G17*x0;
        o[1] = G00*w4 + G02*w3 + G04*w2 + G06*w1
             + G10*x4 + G12*x3 + G14*x2 + G16*x1;
        o[2] = G01*w4 + G03*w3 + G05*w2 + G07*w1
             + G11*x4 + G13*x3 + G15*x2 + G17*x1;
        o[3] = G00*w5 + G02*w4 + G04*w3 + G06*w2
             + G10*x5 + G12*x4 + G14*x3 + G16*x2;
        f32x4* dst = (f32x4*)(orow_base + (size_t)hl * 256) + ow;
        __builtin_nontemporal_store(o, dst);
    }
}

// One Phase-A batch for batch k: 12 loads (6 planes x lo/hi) -> 4 t-values.
#define ABATCH(k) { \
    int x_ = (k) * 16 + xr; int pr_ = x_ / 20; int r_ = x_ - 20 * pr_; \
    int hr_ = h0in + r_; if (hr_ < 0) hr_ += 128; if (hr_ >= 128) hr_ -= 128; \
    const float* lo_ = (pr_ == 0) ? llb : (yb + (size_t)(2 * pr_ - 1) * V); \
    const float* hi_ = yb + (size_t)(2 * pr_) * V; \
    const float* lp_ = lo_ + hr_ * 128 + w4c * 4; \
    const float* hp_ = hi_ + hr_ * 128 + w4c * 4; \
    f32x4 L0 = *(const f32x4*)(lp_ + q0), L1 = *(const f32x4*)(lp_ + q1); \
    f32x4 L2 = *(const f32x4*)(lp_ + q2), L3 = *(const f32x4*)(lp_ + q3); \
    f32x4 L4 = *(const f32x4*)(lp_ + q4), L5 = *(const f32x4*)(lp_ + q5); \
    f32x4 H0 = *(const f32x4*)(hp_ + q0), H1 = *(const f32x4*)(hp_ + q1); \
    f32x4 H2 = *(const f32x4*)(hp_ + q2), H3 = *(const f32x4*)(hp_ + q3); \
    f32x4 H4 = *(const f32x4*)(hp_ + q4), H5 = *(const f32x4*)(hp_ + q5); \
    smem[(k) * 512 + tid] = G01*L3 + G03*L2 + G05*L1 + G07*L0 \
                          + G11*H3 + G13*H2 + G15*H1 + G17*H0; \
    tA1[k] = G00*L4 + G02*L3 + G04*L2 + G06*L1 \
           + G10*H4 + G12*H3 + G14*H2 + G16*H1; \
    tB0[k] = G01*L4 + G03*L3 + G05*L2 + G07*L1 \
           + G11*H4 + G13*H3 + G15*H2 + G17*H1; \
    tB1[k] = G00*L5 + G02*L4 + G04*L3 + G06*L2 \
           + G10*H5 + G12*H4 + G14*H3 + G16*H2; }

#define TSWAP(tarr) { \
    _Pragma("unroll") \
    for (int it_ = 0; it_ < 5; ++it_) smem[it_ * 512 + tid] = (tarr)[it_]; }

__global__ __launch_bounds__(512, 2) void idwt3_l2q_k(
    const float* __restrict__ ll, const float* __restrict__ yh,
    float* __restrict__ out)
{
    constexpr int N = 128;
    constexpr int NN = N * N;
    constexpr size_t V = (size_t)N * N * N;

    __shared__ f32x4 smem[2560];                 // tl[4][20][32]; reused as padded ul

    const int tid  = threadIdx.x;
    const int tile = blockIdx.x;                 // 8 h-tiles
    const int g    = blockIdx.y;                 // 64 m-value pairs (mA=2g, mB=2g+1)
    const int b    = blockIdx.z;                 // 4 batches

    // 6-plane union {2g-2 .. 2g+3} (wrapped)
    const size_t q0 = (size_t)((2 * g - 2 + N) & (N - 1)) * NN;
    const size_t q1 = (size_t)((2 * g - 1 + N) & (N - 1)) * NN;
    const size_t q2 = (size_t)( 2 * g                    ) * NN;
    const size_t q3 = (size_t)((2 * g + 1) & (N - 1)) * NN;
    const size_t q4 = (size_t)((2 * g + 2) & (N - 1)) * NN;
    const size_t q5 = (size_t)((2 * g + 3) & (N - 1)) * NN;

    const int h0in = 16 * tile - 2;
    const float* llb = ll + (size_t)b * V;
    const float* yb  = yh + (size_t)b * 7 * V;
    const int xr  = tid >> 5;
    const int w4c = tid & 31;

    f32x4 tA1[5], tB0[5], tB1[5];                // register stashes (static idx)

    ABATCH(0); ABATCH(1); ABATCH(2); ABATCH(3); ABATCH(4);
    __syncthreads();

    phaseBC_l2(smem, out, b, 4 * g + 0, tile, tid);
    __syncthreads();
    TSWAP(tA1);
    __syncthreads();
    phaseBC_l2(smem, out, b, 4 * g + 1, tile, tid);
    __syncthreads();
    TSWAP(tB0);
    __syncthreads();
    phaseBC_l2(smem, out, b, 4 * g + 2, tile, tid);
    __syncthreads();
    TSWAP(tB1);
    __syncthreads();
    phaseBC_l2(smem, out, b, 4 * g + 3, tile, tid);
}

// ===========================================================================

extern "C" void kernel_launch(void* const* d_in, const int* in_sizes, int n_in,
                              void* d_out, int out_size, void* d_ws, size_t ws_size,
                              hipStream_t stream)
{
    const float* yl  = (const float*)d_in[0];   // (4,1,64,64,64)
    const float* yh1 = (const float*)d_in[1];   // (4,7,128,128,128)
    const float* yh2 = (const float*)d_in[2];   // (4,7,64,64,64)
    float* outf = (float*)d_out;                // (4,1,256,256,256)
    float* ll1  = (float*)d_ws;                 // (4,128,128,128) scratch

    // Level 1 (n=64 -> 128): R7 kernel, 3D grid (best-measured)
    idwt3_fused2_k<6, false><<<dim3(4, 64, 4), 512, 0, stream>>>(yl, yh2, ll1, 0);

    // Level 2 (n=128 -> 256): quad-plane kernel, 2048 blocks, VGPR cap 256
    idwt3_l2q_k<<<dim3(8, 64, 4), 512, 0, stream>>>(ll1, yh1, outf);
}